// Round 1
// baseline (878.694 us; speedup 1.0000x reference)
//
#include <hip/hip_runtime.h>
#include <hip/hip_bf16.h>

#define S_LEN 2048
#define NHEAD 16
#define DHEAD 64
#define EMB   1024
#define NB    4

typedef short s16x8 __attribute__((ext_vector_type(8)));
typedef float f32x4 __attribute__((ext_vector_type(4)));

#define MFMA16(a, b, c) __builtin_amdgcn_mfma_f32_16x16x32_bf16(a, b, c, 0, 0, 0)

__device__ inline unsigned short f2bf(float f) {
    unsigned u = __builtin_bit_cast(unsigned, f);
    u += 0x7FFFu + ((u >> 16) & 1u);   // RNE
    return (unsigned short)(u >> 16);
}

__device__ inline s16x8 cvt8(const float* __restrict__ p) {
    const f32x4* q = (const f32x4*)p;
    f32x4 a = q[0], b = q[1];
    s16x8 r;
    r[0] = (short)f2bf(a[0]); r[1] = (short)f2bf(a[1]);
    r[2] = (short)f2bf(a[2]); r[3] = (short)f2bf(a[3]);
    r[4] = (short)f2bf(b[0]); r[5] = (short)f2bf(b[1]);
    r[6] = (short)f2bf(b[2]); r[7] = (short)f2bf(b[3]);
    return r;
}

// K0: Wo f32 -> bf16 (1024x1024), row-major unchanged
__global__ __launch_bounds__(256) void cvt_wo(const float* __restrict__ Wo,
                                              unsigned short* __restrict__ Wb) {
    int i = (blockIdx.x * 256 + threadIdx.x) * 4;
    f32x4 v = *(const f32x4*)(Wo + i);
    unsigned long long pk = (unsigned long long)f2bf(v[0])
                          | ((unsigned long long)f2bf(v[1]) << 16)
                          | ((unsigned long long)f2bf(v[2]) << 32)
                          | ((unsigned long long)f2bf(v[3]) << 48);
    *(unsigned long long*)(Wb + i) = pk;
}

// K1: per-head projection. x viewed as (B*S*H, 64) row-major; out[m,e] = sum_d x[m,d]*W[e,d].
// isV=0: out[((b*H+h)*S+s)*64 + e]   (Q/K layout)
// isV=1: out[((b*H+h)*64+e)*S + s]   (V transposed for PV B-fragments)
__global__ __launch_bounds__(256) void proj(const float* __restrict__ x,
                                            const float* __restrict__ W,
                                            unsigned short* __restrict__ out,
                                            int isV) {
    int wave = threadIdx.x >> 6, lane = threadIdx.x & 63;
    int g = lane >> 4, c = lane & 15;
    int m0 = (blockIdx.x * 4 + wave) * 16;

    // A fragments: row = m0+c, k = ks*32 + g*8 + j
    s16x8 a0 = cvt8(x + (size_t)(m0 + c) * 64 + g * 8);
    s16x8 a1 = cvt8(x + (size_t)(m0 + c) * 64 + 32 + g * 8);

    const f32x4 fzero = {0.f, 0.f, 0.f, 0.f};
    f32x4 acc[4];
    #pragma unroll
    for (int nt = 0; nt < 4; ++nt) {
        // B[k=d][n=e] = W[e][d]: lane holds e = nt*16+c, d = ks*32 + g*8 + j
        s16x8 b0 = cvt8(W + (size_t)(nt * 16 + c) * 64 + g * 8);
        s16x8 b1 = cvt8(W + (size_t)(nt * 16 + c) * 64 + 32 + g * 8);
        f32x4 z = fzero;
        z = MFMA16(a0, b0, z);
        z = MFMA16(a1, b1, z);
        acc[nt] = z;
    }

    #pragma unroll
    for (int j = 0; j < 4; ++j) {
        int m = m0 + g * 4 + j;                   // D row = (lane>>4)*4 + j
        int h = m & 15, s = (m >> 4) & (S_LEN - 1), b = m >> 15;
        #pragma unroll
        for (int nt = 0; nt < 4; ++nt) {
            int col = nt * 16 + c;                // D col = lane&15 (+16*nt)
            unsigned short v = f2bf(acc[nt][j]);
            size_t addr = isV
                ? ((size_t)((b * NHEAD + h) * DHEAD + col)) * S_LEN + s
                : ((size_t)((b * NHEAD + h) * S_LEN + s)) * DHEAD + col;
            out[addr] = v;
        }
    }
}

// K2: flash attention. Grid: (S/64 q-tiles, B*H). 4 waves/block, 16 q-rows/wave, KBLK=32.
__global__ __launch_bounds__(256) void attn(const unsigned short* __restrict__ Qp,
                                            const unsigned short* __restrict__ Kp,
                                            const unsigned short* __restrict__ Vt,
                                            const int* __restrict__ mask,
                                            unsigned short* __restrict__ Oa) {
    __shared__ unsigned short Plds[4][16 * 40];   // 16 rows x 32 cols, pad to 40 (80B rows, 16B aligned)
    int wave = threadIdx.x >> 6, lane = threadIdx.x & 63;
    int g = lane >> 4, c = lane & 15;
    int bh = blockIdx.y, b = bh >> 4, h = bh & 15;
    int q0 = blockIdx.x * 64 + wave * 16;

    const unsigned short* Qb = Qp + (size_t)bh * S_LEN * DHEAD;
    const unsigned short* Kb = Kp + (size_t)bh * S_LEN * DHEAD;
    const unsigned short* Vb = Vt + (size_t)bh * DHEAD * S_LEN;
    const int* mb = mask + (size_t)b * S_LEN * S_LEN;

    // Q fragments hoisted (wave-invariant over the kv loop)
    s16x8 aq0 = *(const s16x8*)(Qb + (size_t)(q0 + c) * 64 + g * 8);
    s16x8 aq1 = *(const s16x8*)(Qb + (size_t)(q0 + c) * 64 + 32 + g * 8);

    const f32x4 fzero = {0.f, 0.f, 0.f, 0.f};
    f32x4 acc[4];
    float m_run[4], l_run[4];
    #pragma unroll
    for (int nt = 0; nt < 4; ++nt) acc[nt] = fzero;
    #pragma unroll
    for (int j = 0; j < 4; ++j) { m_run[j] = -1e30f; l_run[j] = 0.f; }

    unsigned short* Pw = Plds[wave];

    for (int kt = 0; kt < S_LEN / 32; ++kt) {
        int k0 = kt * 32;
        // scores: two 16x16 tiles, K-dim 64 = 2 MFMA each
        const unsigned short* K0p = Kb + (size_t)(k0 + c) * 64 + g * 8;
        const unsigned short* K1p = Kb + (size_t)(k0 + 16 + c) * 64 + g * 8;
        s16x8 bk00 = *(const s16x8*)(K0p);
        s16x8 bk01 = *(const s16x8*)(K0p + 32);
        s16x8 bk10 = *(const s16x8*)(K1p);
        s16x8 bk11 = *(const s16x8*)(K1p + 32);
        f32x4 s0 = MFMA16(aq0, bk00, fzero);
        s0 = MFMA16(aq1, bk01, s0);
        f32x4 s1 = MFMA16(aq0, bk10, fzero);
        s1 = MFMA16(aq1, bk11, s1);

        const float sc = 0.03125f;  // 1/sqrt(1024)
        float p0[4], p1[4], t[4];
        #pragma unroll
        for (int j = 0; j < 4; ++j) {
            int q = q0 + g * 4 + j;
            const int* mrow = mb + (size_t)q * S_LEN + k0;
            float v0 = mrow[c]      ? s0[j] * sc : -1e20f;
            float v1 = mrow[16 + c] ? s1[j] * sc : -1e20f;
            s0[j] = v0; s1[j] = v1;
            t[j] = fmaxf(v0, v1);
        }
        // row max across the 16 lanes of each row group
        #pragma unroll
        for (int off = 1; off < 16; off <<= 1) {
            #pragma unroll
            for (int j = 0; j < 4; ++j) t[j] = fmaxf(t[j], __shfl_xor(t[j], off));
        }
        float f[4], u[4];
        #pragma unroll
        for (int j = 0; j < 4; ++j) {
            float mn = fmaxf(m_run[j], t[j]);
            f[j] = __expf(m_run[j] - mn);
            m_run[j] = mn;
            p0[j] = __expf(s0[j] - mn);
            p1[j] = __expf(s1[j] - mn);
            u[j] = p0[j] + p1[j];
        }
        #pragma unroll
        for (int off = 1; off < 16; off <<= 1) {
            #pragma unroll
            for (int j = 0; j < 4; ++j) u[j] += __shfl_xor(u[j], off);
        }
        #pragma unroll
        for (int j = 0; j < 4; ++j) l_run[j] = l_run[j] * f[j] + u[j];
        #pragma unroll
        for (int nt = 0; nt < 4; ++nt) {
            #pragma unroll
            for (int j = 0; j < 4; ++j) acc[nt][j] *= f[j];
        }

        // P: D-layout -> A-layout via per-wave LDS (same-wave, in-order DS pipe: no barrier)
        #pragma unroll
        for (int j = 0; j < 4; ++j) {
            int r = g * 4 + j;
            Pw[r * 40 + c]      = f2bf(p0[j]);
            Pw[r * 40 + 16 + c] = f2bf(p1[j]);
        }
        s16x8 ap = *(const s16x8*)(Pw + c * 40 + g * 8);

        // PV: B[k][n=d] = Vt[d][k0+k], contiguous 16B loads
        #pragma unroll
        for (int nt = 0; nt < 4; ++nt) {
            s16x8 bv = *(const s16x8*)(Vb + (size_t)(nt * 16 + c) * S_LEN + k0 + g * 8);
            acc[nt] = MFMA16(ap, bv, acc[nt]);
        }
    }

    #pragma unroll
    for (int j = 0; j < 4; ++j) {
        int q = q0 + g * 4 + j;
        float inv = 1.f / l_run[j];
        #pragma unroll
        for (int nt = 0; nt < 4; ++nt) {
            size_t addr = ((size_t)(b * S_LEN + q)) * EMB + h * DHEAD + nt * 16 + c;
            Oa[addr] = f2bf(acc[nt][j] * inv);
        }
    }
}

// K3: out = Oa(8192x1024,bf16) @ Wo^T + bo, f32 out. 64x64 tile/block, 16x64 per wave.
__global__ __launch_bounds__(256) void outproj(const unsigned short* __restrict__ A,
                                               const unsigned short* __restrict__ Wb,
                                               const float* __restrict__ bo,
                                               float* __restrict__ out) {
    int wave = threadIdx.x >> 6, lane = threadIdx.x & 63;
    int g = lane >> 4, c = lane & 15;
    int r0 = blockIdx.x * 64 + wave * 16;
    int n0 = blockIdx.y * 64;

    const f32x4 fzero = {0.f, 0.f, 0.f, 0.f};
    f32x4 acc[4];
    #pragma unroll
    for (int nt = 0; nt < 4; ++nt) acc[nt] = fzero;

    for (int kt = 0; kt < EMB / 32; ++kt) {
        int kb = kt * 32;
        s16x8 a = *(const s16x8*)(A + (size_t)(r0 + c) * EMB + kb + g * 8);
        #pragma unroll
        for (int nt = 0; nt < 4; ++nt) {
            // B[k][n] = Wo[n][k]
            s16x8 bw = *(const s16x8*)(Wb + (size_t)(n0 + nt * 16 + c) * EMB + kb + g * 8);
            acc[nt] = MFMA16(a, bw, acc[nt]);
        }
    }
    #pragma unroll
    for (int j = 0; j < 4; ++j) {
        int row = r0 + g * 4 + j;
        #pragma unroll
        for (int nt = 0; nt < 4; ++nt) {
            int col = n0 + nt * 16 + c;
            out[(size_t)row * EMB + col] = acc[nt][j] + bo[col];
        }
    }
}

extern "C" void kernel_launch(void* const* d_in, const int* in_sizes, int n_in,
                              void* d_out, int out_size, void* d_ws, size_t ws_size,
                              hipStream_t stream) {
    (void)in_sizes; (void)n_in; (void)out_size; (void)ws_size;
    const float* values  = (const float*)d_in[0];
    const float* keys    = (const float*)d_in[1];
    const float* queries = (const float*)d_in[2];
    const int*   mask    = (const int*)d_in[3];
    const float* Wv = (const float*)d_in[4];
    const float* Wk = (const float*)d_in[5];
    const float* Wq = (const float*)d_in[6];
    const float* Wo = (const float*)d_in[7];
    const float* bo = (const float*)d_in[8];
    float* out = (float*)d_out;

    // workspace: Qp, Kp, Vt, Oa (each B*H*S*64 = 8M bf16 = 16 MiB), Wb (1M bf16 = 2 MiB) => 66 MiB
    unsigned short* Qp = (unsigned short*)d_ws;
    unsigned short* Kp = Qp + (size_t)8 * 1024 * 1024;
    unsigned short* Vt = Kp + (size_t)8 * 1024 * 1024;
    unsigned short* Oa = Vt + (size_t)8 * 1024 * 1024;
    unsigned short* Wb = Oa + (size_t)8 * 1024 * 1024;

    cvt_wo<<<1024, 256, 0, stream>>>(Wo, Wb);
    proj<<<2048, 256, 0, stream>>>(queries, Wq, Qp, 0);
    proj<<<2048, 256, 0, stream>>>(keys,    Wk, Kp, 0);
    proj<<<2048, 256, 0, stream>>>(values,  Wv, Vt, 1);
    attn<<<dim3(32, 64), 256, 0, stream>>>(Qp, Kp, Vt, mask, Oa);
    outproj<<<dim3(128, 16), 256, 0, stream>>>(Oa, Wb, bo, out);
}

// Round 6
// 797.662 us; speedup vs baseline: 1.1016x; 1.1016x over previous
//
#include <hip/hip_runtime.h>
#include <hip/hip_bf16.h>

#define S_LEN 2048
#define NHEAD 16
#define DHEAD 64
#define EMB   1024
#define NB    4

typedef short s16x8 __attribute__((ext_vector_type(8)));
typedef float f32x4 __attribute__((ext_vector_type(4)));

#define MFMA16(a, b, c) __builtin_amdgcn_mfma_f32_16x16x32_bf16(a, b, c, 0, 0, 0)

#if __has_builtin(__builtin_amdgcn_exp2f)
#define EXP2(x) __builtin_amdgcn_exp2f(x)
#else
#define EXP2(x) exp2f(x)
#endif

__device__ inline unsigned short f2bf(float f) {
    unsigned u = __builtin_bit_cast(unsigned, f);
    u += 0x7FFFu + ((u >> 16) & 1u);   // RNE
    return (unsigned short)(u >> 16);
}

__device__ inline s16x8 cvt8(const float* __restrict__ p) {
    const f32x4* q = (const f32x4*)p;
    f32x4 a = q[0], b = q[1];
    s16x8 r;
    r[0] = (short)f2bf(a[0]); r[1] = (short)f2bf(a[1]);
    r[2] = (short)f2bf(a[2]); r[3] = (short)f2bf(a[3]);
    r[4] = (short)f2bf(b[0]); r[5] = (short)f2bf(b[1]);
    r[6] = (short)f2bf(b[2]); r[7] = (short)f2bf(b[3]);
    return r;
}

// K0: Wo f32 -> bf16 (1024x1024)
__global__ __launch_bounds__(256) void cvt_wo(const float* __restrict__ Wo,
                                              unsigned short* __restrict__ Wb) {
    int i = (blockIdx.x * 256 + threadIdx.x) * 4;
    f32x4 v = *(const f32x4*)(Wo + i);
    unsigned long long pk = (unsigned long long)f2bf(v[0])
                          | ((unsigned long long)f2bf(v[1]) << 16)
                          | ((unsigned long long)f2bf(v[2]) << 32)
                          | ((unsigned long long)f2bf(v[3]) << 48);
    *(unsigned long long*)(Wb + i) = pk;
}

// K1: pack mask int32 -> bit mask. word w <-> mask[w*64 .. w*64+63]
__global__ __launch_bounds__(256) void packmask(const int* __restrict__ mask,
                                                unsigned long long* __restrict__ Mp) {
    int wid = (blockIdx.x * 256 + (int)threadIdx.x) >> 6;
    int lane = threadIdx.x & 63;
    #pragma unroll 4
    for (int i = 0; i < 64; ++i) {
        size_t w = (size_t)wid * 64 + i;
        int m = mask[w * 64 + lane];
        unsigned long long bal = __ballot(m != 0);
        if (lane == 0) Mp[w] = bal;
    }
}

// K2: Q/K projection. out[((b*H+h)*S+s)*64 + e] = scale * sum_d x[m,d]*W[e,d]
__global__ __launch_bounds__(256) void projqk(const float* __restrict__ x,
                                              const float* __restrict__ W,
                                              unsigned short* __restrict__ out,
                                              float scale) {
    int wave = threadIdx.x >> 6, lane = threadIdx.x & 63;
    int g = lane >> 4, c = lane & 15;
    int m0 = (blockIdx.x * 4 + wave) * 16;

    s16x8 a0 = cvt8(x + (size_t)(m0 + c) * 64 + g * 8);
    s16x8 a1 = cvt8(x + (size_t)(m0 + c) * 64 + 32 + g * 8);

    const f32x4 fzero = {0.f, 0.f, 0.f, 0.f};
    f32x4 acc[4];
    #pragma unroll
    for (int nt = 0; nt < 4; ++nt) {
        s16x8 b0 = cvt8(W + (size_t)(nt * 16 + c) * 64 + g * 8);
        s16x8 b1 = cvt8(W + (size_t)(nt * 16 + c) * 64 + 32 + g * 8);
        f32x4 z = fzero;
        z = MFMA16(a0, b0, z);
        z = MFMA16(a1, b1, z);
        acc[nt] = z;
    }
    #pragma unroll
    for (int j = 0; j < 4; ++j) {
        int m = m0 + g * 4 + j;
        int h = m & 15, s = (m >> 4) & (S_LEN - 1), b = m >> 15;
        #pragma unroll
        for (int nt = 0; nt < 4; ++nt) {
            int col = nt * 16 + c;
            out[((size_t)((b * NHEAD + h) * S_LEN + s)) * DHEAD + col] = f2bf(acc[nt][j] * scale);
        }
    }
}

// K3: V projection, written transposed: Vt[((b*H+h)*64+e)*S + s].
// GEMM with M=e (A=W), N=s (B[k=d][n=s] = x[s,h,d]).
__global__ __launch_bounds__(256) void projv(const float* __restrict__ x,
                                             const float* __restrict__ W,
                                             unsigned short* __restrict__ Vt) {
    int wave = threadIdx.x >> 6, lane = threadIdx.x & 63;
    int g = lane >> 4, c = lane & 15;
    int s0 = blockIdx.x * 64;
    int bh = blockIdx.y, b = bh >> 4, h = bh & 15;
    int m0 = wave * 16;   // e-range

    s16x8 a0 = cvt8(W + (size_t)(m0 + c) * 64 + g * 8);
    s16x8 a1 = cvt8(W + (size_t)(m0 + c) * 64 + 32 + g * 8);

    const f32x4 fzero = {0.f, 0.f, 0.f, 0.f};
    f32x4 acc[4];
    #pragma unroll
    for (int nt = 0; nt < 4; ++nt) {
        int s = s0 + nt * 16 + c;
        const float* xr = x + ((size_t)(b * S_LEN + s) * NHEAD + h) * DHEAD;
        s16x8 b0 = cvt8(xr + g * 8);          // B-fragment k-slice is d ∈ [8g, 8g+8)
        s16x8 b1 = cvt8(xr + 32 + g * 8);     // ditto for k ∈ [32,64)
        f32x4 z = fzero;
        z = MFMA16(a0, b0, z);
        z = MFMA16(a1, b1, z);
        acc[nt] = z;
    }
    #pragma unroll
    for (int j = 0; j < 4; ++j) {
        int e = m0 + g * 4 + j;
        unsigned short* Vr = Vt + ((size_t)(bh * DHEAD) + e) * S_LEN;
        #pragma unroll
        for (int nt = 0; nt < 4; ++nt) {
            Vr[s0 + nt * 16 + c] = f2bf(acc[nt][j]);
        }
    }
}

// K4: flash attention, static-max. Grid (S/64, B*H), 4 waves/block, 16 q-rows/wave, KBLK=64.
__global__ __launch_bounds__(256) void attn(const unsigned short* __restrict__ Qp,
                                            const unsigned short* __restrict__ Kp,
                                            const unsigned short* __restrict__ Vt,
                                            const unsigned long long* __restrict__ Mp,
                                            unsigned short* __restrict__ Oa) {
    __shared__ unsigned short Plds[4][16 * 72];   // 16 q-rows x 64 k-cols, pad to 72
    int wave = threadIdx.x >> 6, lane = threadIdx.x & 63;
    int g = lane >> 4, c = lane & 15;
    int bh = blockIdx.y, b = bh >> 4, h = bh & 15;
    int q0 = blockIdx.x * 64 + wave * 16;

    const unsigned short* Qb = Qp + (size_t)bh * S_LEN * DHEAD;
    const unsigned short* Kb = Kp + (size_t)bh * S_LEN * DHEAD;
    const unsigned short* Vb = Vt + (size_t)bh * DHEAD * S_LEN;
    const unsigned long long* mb = Mp + (size_t)b * S_LEN * (S_LEN / 64);

    // Q fragments hoisted (Q pre-scaled by log2(e)/32 in projqk)
    s16x8 aq0 = *(const s16x8*)(Qb + (size_t)(q0 + c) * 64 + g * 8);
    s16x8 aq1 = *(const s16x8*)(Qb + (size_t)(q0 + c) * 64 + 32 + g * 8);

    const f32x4 fzero = {0.f, 0.f, 0.f, 0.f};
    f32x4 acc[4], accl;
    #pragma unroll
    for (int nt = 0; nt < 4; ++nt) acc[nt] = fzero;
    accl = fzero;

    s16x8 ones;
    #pragma unroll
    for (int i = 0; i < 8; ++i) ones[i] = (short)0x3F80;   // bf16 1.0

    unsigned short* Pw = Plds[wave];

    for (int kt = 0; kt < S_LEN / 64; ++kt) {
        int k0 = kt * 64;

        // mask words (L2-resident 2MB table; broadcast across the 16 lanes of a group)
        unsigned long long mw[4];
        #pragma unroll
        for (int j = 0; j < 4; ++j)
            mw[j] = mb[(size_t)(q0 + g * 4 + j) * (S_LEN / 64) + kt];

        // scores: 4 16x16 tiles over KBLK=64
        f32x4 sc[4];
        #pragma unroll
        for (int nt = 0; nt < 4; ++nt) {
            const unsigned short* Kpp = Kb + (size_t)(k0 + nt * 16 + c) * 64 + g * 8;
            s16x8 b0 = *(const s16x8*)(Kpp);
            s16x8 b1 = *(const s16x8*)(Kpp + 32);
            f32x4 z = MFMA16(aq0, b0, fzero);
            sc[nt] = MFMA16(aq1, b1, z);
        }

        // p = exp2(s) * maskbit  (no max subtraction: |s| bounded ~1.5)
        #pragma unroll
        for (int j = 0; j < 4; ++j) {
            unsigned wlo = (unsigned)mw[j];
            unsigned whi = (unsigned)(mw[j] >> 32);
            int r = g * 4 + j;
            #pragma unroll
            for (int nt = 0; nt < 4; ++nt) {
                float e = EXP2(sc[nt][j]);
                unsigned part = (nt < 2) ? wlo : whi;
                float p = e * (float)((part >> ((nt & 1) * 16 + c)) & 1u);
                Pw[r * 72 + nt * 16 + c] = __builtin_bit_cast(unsigned short, __float2bfloat16(p));
            }
        }

        // P fragments (A-layout) via same-wave LDS transpose (no barrier needed)
        s16x8 ap0 = *(const s16x8*)(Pw + c * 72 + g * 8);
        s16x8 ap1 = *(const s16x8*)(Pw + c * 72 + 32 + g * 8);

        // row-sum via ones-MFMA (replaces shuffle reduction)
        accl = MFMA16(ap0, ones, accl);
        accl = MFMA16(ap1, ones, accl);

        // PV
        #pragma unroll
        for (int nt = 0; nt < 4; ++nt) {
            const unsigned short* Vpp = Vb + (size_t)(nt * 16 + c) * S_LEN + k0 + g * 8;
            s16x8 bv0 = *(const s16x8*)(Vpp);
            s16x8 bv1 = *(const s16x8*)(Vpp + 32);
            acc[nt] = MFMA16(ap0, bv0, acc[nt]);
            acc[nt] = MFMA16(ap1, bv1, acc[nt]);
        }
    }

    #pragma unroll
    for (int j = 0; j < 4; ++j) {
        int q = q0 + g * 4 + j;
        float inv = 1.f / accl[j];
        #pragma unroll
        for (int nt = 0; nt < 4; ++nt) {
            size_t addr = ((size_t)(b * S_LEN + q)) * EMB + h * DHEAD + nt * 16 + c;
            Oa[addr] = f2bf(acc[nt][j] * inv);
        }
    }
}

// K5: out = Oa(8192x1024,bf16) @ Wo^T + bo. 64x64 per wave, 256x64 per block.
__global__ __launch_bounds__(256) void outproj(const unsigned short* __restrict__ A,
                                               const unsigned short* __restrict__ Wb,
                                               const float* __restrict__ bo,
                                               float* __restrict__ out) {
    int wave = threadIdx.x >> 6, lane = threadIdx.x & 63;
    int g = lane >> 4, c = lane & 15;
    int r0 = blockIdx.x * 256 + wave * 64;
    int n0 = blockIdx.y * 64;

    float bias[4];
    #pragma unroll
    for (int nt = 0; nt < 4; ++nt) bias[nt] = bo[n0 + nt * 16 + c];

    const f32x4 fzero = {0.f, 0.f, 0.f, 0.f};
    f32x4 acc[4][4];   // [mi][nt]
    #pragma unroll
    for (int mi = 0; mi < 4; ++mi)
        #pragma unroll
        for (int nt = 0; nt < 4; ++nt) acc[mi][nt] = fzero;

    for (int kt = 0; kt < EMB / 32; ++kt) {
        int kb = kt * 32;
        s16x8 a[4], bw[4];
        #pragma unroll
        for (int mi = 0; mi < 4; ++mi)
            a[mi] = *(const s16x8*)(A + (size_t)(r0 + mi * 16 + c) * EMB + kb + g * 8);
        #pragma unroll
        for (int nt = 0; nt < 4; ++nt)
            bw[nt] = *(const s16x8*)(Wb + (size_t)(n0 + nt * 16 + c) * EMB + kb + g * 8);
        #pragma unroll
        for (int mi = 0; mi < 4; ++mi)
            #pragma unroll
            for (int nt = 0; nt < 4; ++nt)
                acc[mi][nt] = MFMA16(a[mi], bw[nt], acc[mi][nt]);
    }
    #pragma unroll
    for (int mi = 0; mi < 4; ++mi)
        #pragma unroll
        for (int j = 0; j < 4; ++j) {
            int row = r0 + mi * 16 + g * 4 + j;
            #pragma unroll
            for (int nt = 0; nt < 4; ++nt)
                out[(size_t)row * EMB + n0 + nt * 16 + c] = acc[mi][nt][j] + bias[nt];
        }
}

extern "C" void kernel_launch(void* const* d_in, const int* in_sizes, int n_in,
                              void* d_out, int out_size, void* d_ws, size_t ws_size,
                              hipStream_t stream) {
    (void)in_sizes; (void)n_in; (void)out_size; (void)ws_size;
    const float* values  = (const float*)d_in[0];
    const float* keys    = (const float*)d_in[1];
    const float* queries = (const float*)d_in[2];
    const int*   mask    = (const int*)d_in[3];
    const float* Wv = (const float*)d_in[4];
    const float* Wk = (const float*)d_in[5];
    const float* Wq = (const float*)d_in[6];
    const float* Wo = (const float*)d_in[7];
    const float* bo = (const float*)d_in[8];
    float* out = (float*)d_out;

    // ws: Qp, Kp, Vt, Oa (16 MiB each), Wb (2 MiB), Mp (2 MiB) = 68 MiB
    unsigned short* Qp = (unsigned short*)d_ws;
    unsigned short* Kp = Qp + (size_t)8 * 1024 * 1024;
    unsigned short* Vt = Kp + (size_t)8 * 1024 * 1024;
    unsigned short* Oa = Vt + (size_t)8 * 1024 * 1024;
    unsigned short* Wb = Oa + (size_t)8 * 1024 * 1024;
    unsigned long long* Mp = (unsigned long long*)(Wb + (size_t)1024 * 1024);

    const float QSCALE = 0.045084220027780106f;   // log2(e) / sqrt(1024)

    cvt_wo<<<1024, 256, 0, stream>>>(Wo, Wb);
    packmask<<<1024, 256, 0, stream>>>(mask, Mp);
    projqk<<<2048, 256, 0, stream>>>(queries, Wq, Qp, QSCALE);
    projqk<<<2048, 256, 0, stream>>>(keys,    Wk, Kp, 1.0f);
    projv<<<dim3(32, 64), 256, 0, stream>>>(values, Wv, Vt);
    attn<<<dim3(32, 64), 256, 0, stream>>>(Qp, Kp, Vt, Mp, Oa);
    outproj<<<dim3(32, 16), 256, 0, stream>>>(Oa, Wb, bo, out);
}

// Round 7
// 779.193 us; speedup vs baseline: 1.1277x; 1.0237x over previous
//
#include <hip/hip_runtime.h>
#include <hip/hip_bf16.h>

#define S_LEN 2048
#define NHEAD 16
#define DHEAD 64
#define EMB   1024
#define NB    4

typedef short s16x8 __attribute__((ext_vector_type(8)));
typedef float f32x4 __attribute__((ext_vector_type(4)));

#define MFMA16(a, b, c) __builtin_amdgcn_mfma_f32_16x16x32_bf16(a, b, c, 0, 0, 0)

#if __has_builtin(__builtin_amdgcn_exp2f)
#define EXP2(x) __builtin_amdgcn_exp2f(x)
#else
#define EXP2(x) exp2f(x)
#endif

__device__ inline unsigned short f2bf(float f) {
    return __builtin_bit_cast(unsigned short, __float2bfloat16(f));   // HW RNE (v_cvt_pk fusable)
}

__device__ inline s16x8 cvt8(const float* __restrict__ p) {
    const f32x4* q = (const f32x4*)p;
    f32x4 a = q[0], b = q[1];
    s16x8 r;
    r[0] = (short)f2bf(a[0]); r[1] = (short)f2bf(a[1]);
    r[2] = (short)f2bf(a[2]); r[3] = (short)f2bf(a[3]);
    r[4] = (short)f2bf(b[0]); r[5] = (short)f2bf(b[1]);
    r[6] = (short)f2bf(b[2]); r[7] = (short)f2bf(b[3]);
    return r;
}

// K0: f32 -> bf16 copy, 4 elems/thread (used for Wo with grid 1024, and Wq/Wk/Wv with grid 4)
__global__ __launch_bounds__(256) void cvt_wo(const float* __restrict__ Wo,
                                              unsigned short* __restrict__ Wb) {
    int i = (blockIdx.x * 256 + threadIdx.x) * 4;
    f32x4 v = *(const f32x4*)(Wo + i);
    unsigned long long pk = (unsigned long long)f2bf(v[0])
                          | ((unsigned long long)f2bf(v[1]) << 16)
                          | ((unsigned long long)f2bf(v[2]) << 32)
                          | ((unsigned long long)f2bf(v[3]) << 48);
    *(unsigned long long*)(Wb + i) = pk;
}

// K1: pack mask int32 -> bit mask. 16 words per wave, 4096 blocks.
__global__ __launch_bounds__(256) void packmask(const int* __restrict__ mask,
                                                unsigned long long* __restrict__ Mp) {
    int wid0 = (blockIdx.x * 4 + ((int)threadIdx.x >> 6)) * 16;
    int lane = threadIdx.x & 63;
    #pragma unroll 8
    for (int i = 0; i < 16; ++i) {
        size_t w = (size_t)wid0 + i;
        int m = mask[w * 64 + lane];
        unsigned long long bal = __ballot(m != 0);
        if (lane == 0) Mp[w] = bal;
    }
}

// K2: Q/K projection (W pre-converted bf16). out[((b*H+h)*S+s)*64 + e]
__global__ __launch_bounds__(256) void projqk(const float* __restrict__ x,
                                              const unsigned short* __restrict__ W3,
                                              unsigned short* __restrict__ out,
                                              float scale) {
    int wave = threadIdx.x >> 6, lane = threadIdx.x & 63;
    int g = lane >> 4, c = lane & 15;
    int m0 = (blockIdx.x * 4 + wave) * 16;

    s16x8 a0 = cvt8(x + (size_t)(m0 + c) * 64 + g * 8);
    s16x8 a1 = cvt8(x + (size_t)(m0 + c) * 64 + 32 + g * 8);

    const f32x4 fzero = {0.f, 0.f, 0.f, 0.f};
    f32x4 acc[4];
    #pragma unroll
    for (int nt = 0; nt < 4; ++nt) {
        s16x8 b0 = *(const s16x8*)(W3 + (size_t)(nt * 16 + c) * 64 + g * 8);
        s16x8 b1 = *(const s16x8*)(W3 + (size_t)(nt * 16 + c) * 64 + 32 + g * 8);
        f32x4 z = fzero;
        z = MFMA16(a0, b0, z);
        z = MFMA16(a1, b1, z);
        acc[nt] = z;
    }
    #pragma unroll
    for (int j = 0; j < 4; ++j) {
        int m = m0 + g * 4 + j;
        int h = m & 15, s = (m >> 4) & (S_LEN - 1), b = m >> 15;
        #pragma unroll
        for (int nt = 0; nt < 4; ++nt) {
            int col = nt * 16 + c;
            out[((size_t)((b * NHEAD + h) * S_LEN + s)) * DHEAD + col] = f2bf(acc[nt][j] * scale);
        }
    }
}

// K3: V projection, written transposed: Vt[((b*H+h)*64+e)*S + s]
__global__ __launch_bounds__(256) void projv(const float* __restrict__ x,
                                             const unsigned short* __restrict__ W3,
                                             unsigned short* __restrict__ Vt) {
    int wave = threadIdx.x >> 6, lane = threadIdx.x & 63;
    int g = lane >> 4, c = lane & 15;
    int s0 = blockIdx.x * 64;
    int bh = blockIdx.y, b = bh >> 4, h = bh & 15;
    int m0 = wave * 16;   // e-range

    s16x8 a0 = *(const s16x8*)(W3 + (size_t)(m0 + c) * 64 + g * 8);
    s16x8 a1 = *(const s16x8*)(W3 + (size_t)(m0 + c) * 64 + 32 + g * 8);

    const f32x4 fzero = {0.f, 0.f, 0.f, 0.f};
    f32x4 acc[4];
    #pragma unroll
    for (int nt = 0; nt < 4; ++nt) {
        int s = s0 + nt * 16 + c;
        const float* xr = x + ((size_t)(b * S_LEN + s) * NHEAD + h) * DHEAD;
        s16x8 b0 = cvt8(xr + g * 8);          // B-fragment k-slice d ∈ [8g, 8g+8)
        s16x8 b1 = cvt8(xr + 32 + g * 8);
        f32x4 z = fzero;
        z = MFMA16(a0, b0, z);
        z = MFMA16(a1, b1, z);
        acc[nt] = z;
    }
    #pragma unroll
    for (int j = 0; j < 4; ++j) {
        int e = m0 + g * 4 + j;
        unsigned short* Vr = Vt + ((size_t)(bh * DHEAD) + e) * S_LEN;
        #pragma unroll
        for (int nt = 0; nt < 4; ++nt) {
            Vr[s0 + nt * 16 + c] = f2bf(acc[nt][j]);
        }
    }
}

// K4: flash attention, static-max, 1-deep register-prefetch pipeline (no barriers).
// Grid (S/64, B*H), 4 waves/block, 16 q-rows/wave, KBLK=64. ~2 waves/SIMD by design.
__global__ __launch_bounds__(256, 2) void attn(const unsigned short* __restrict__ Qp,
                                               const unsigned short* __restrict__ Kp,
                                               const unsigned short* __restrict__ Vt,
                                               const unsigned long long* __restrict__ Mp,
                                               unsigned short* __restrict__ Oa) {
    __shared__ unsigned short Plds[4][16 * 72];
    int wave = threadIdx.x >> 6, lane = threadIdx.x & 63;
    int g = lane >> 4, c = lane & 15;
    int bh = blockIdx.y, b = bh >> 4, h = bh & 15;
    int q0 = blockIdx.x * 64 + wave * 16;

    const unsigned short* Qb = Qp + (size_t)bh * S_LEN * DHEAD;
    const unsigned short* Kb = Kp + (size_t)bh * S_LEN * DHEAD;
    const unsigned short* Vb = Vt + (size_t)bh * DHEAD * S_LEN;
    const unsigned long long* mb = Mp + (size_t)b * S_LEN * (S_LEN / 64);

    s16x8 aq0 = *(const s16x8*)(Qb + (size_t)(q0 + c) * 64 + g * 8);
    s16x8 aq1 = *(const s16x8*)(Qb + (size_t)(q0 + c) * 64 + 32 + g * 8);

    const f32x4 fzero = {0.f, 0.f, 0.f, 0.f};
    f32x4 acc[4], accl;
    #pragma unroll
    for (int nt = 0; nt < 4; ++nt) acc[nt] = fzero;
    accl = fzero;

    s16x8 ones;
    #pragma unroll
    for (int i = 0; i < 8; ++i) ones[i] = (short)0x3F80;   // bf16 1.0

    unsigned short* Pw = Plds[wave];

    // double-buffered prefetch register sets (named — no runtime indexing, rule #20)
    s16x8 kA[4][2], vA[4][2], kB[4][2], vB[4][2];
    unsigned long long mA[4], mB[4];

    auto LOAD = [&](s16x8 (&kf)[4][2], s16x8 (&vf)[4][2],
                    unsigned long long (&mw)[4], int kt) {
        int k0 = kt * 64;
        #pragma unroll
        for (int nt = 0; nt < 4; ++nt) {
            const unsigned short* Kpp = Kb + (size_t)(k0 + nt * 16 + c) * 64 + g * 8;
            kf[nt][0] = *(const s16x8*)(Kpp);
            kf[nt][1] = *(const s16x8*)(Kpp + 32);
            const unsigned short* Vpp = Vb + (size_t)(nt * 16 + c) * S_LEN + k0 + g * 8;
            vf[nt][0] = *(const s16x8*)(Vpp);
            vf[nt][1] = *(const s16x8*)(Vpp + 32);
        }
        #pragma unroll
        for (int j = 0; j < 4; ++j)
            mw[j] = mb[(size_t)(q0 + g * 4 + j) * (S_LEN / 64) + kt];
    };

    auto BODY = [&](s16x8 (&kf)[4][2], s16x8 (&vf)[4][2],
                    unsigned long long (&mw)[4]) {
        f32x4 sc[4];
        #pragma unroll
        for (int nt = 0; nt < 4; ++nt) {
            f32x4 z = MFMA16(aq0, kf[nt][0], fzero);
            sc[nt] = MFMA16(aq1, kf[nt][1], z);
        }
        #pragma unroll
        for (int j = 0; j < 4; ++j) {
            unsigned wlo = (unsigned)mw[j];
            unsigned whi = (unsigned)(mw[j] >> 32);
            int r = g * 4 + j;
            #pragma unroll
            for (int nt = 0; nt < 4; ++nt) {
                float e = EXP2(sc[nt][j]);
                unsigned part = (nt < 2) ? wlo : whi;
                float p = e * (float)((part >> ((nt & 1) * 16 + c)) & 1u);
                Pw[r * 72 + nt * 16 + c] = f2bf(p);
            }
        }
        s16x8 ap0 = *(const s16x8*)(Pw + c * 72 + g * 8);
        s16x8 ap1 = *(const s16x8*)(Pw + c * 72 + 32 + g * 8);
        accl = MFMA16(ap0, ones, accl);
        accl = MFMA16(ap1, ones, accl);
        #pragma unroll
        for (int nt = 0; nt < 4; ++nt) {
            acc[nt] = MFMA16(ap0, vf[nt][0], acc[nt]);
            acc[nt] = MFMA16(ap1, vf[nt][1], acc[nt]);
        }
    };

    LOAD(kA, vA, mA, 0);
    for (int kt = 0; kt < S_LEN / 64; kt += 2) {
        LOAD(kB, vB, mB, kt + 1);            // prefetch kt+1 while computing kt
        BODY(kA, vA, mA);
        if (kt + 2 < S_LEN / 64) LOAD(kA, vA, mA, kt + 2);
        BODY(kB, vB, mB);
    }

    #pragma unroll
    for (int j = 0; j < 4; ++j) {
        int q = q0 + g * 4 + j;
        float inv = 1.f / accl[j];
        #pragma unroll
        for (int nt = 0; nt < 4; ++nt) {
            size_t addr = ((size_t)(b * S_LEN + q)) * EMB + h * DHEAD + nt * 16 + c;
            Oa[addr] = f2bf(acc[nt][j] * inv);
        }
    }
}

// K5: out = Oa(8192x1024,bf16) @ Wo^T + bo, with 1-deep register prefetch.
__global__ __launch_bounds__(256, 2) void outproj(const unsigned short* __restrict__ A,
                                                  const unsigned short* __restrict__ Wb,
                                                  const float* __restrict__ bo,
                                                  float* __restrict__ out) {
    int wave = threadIdx.x >> 6, lane = threadIdx.x & 63;
    int g = lane >> 4, c = lane & 15;
    int r0 = blockIdx.x * 256 + wave * 64;
    int n0 = blockIdx.y * 64;

    float bias[4];
    #pragma unroll
    for (int nt = 0; nt < 4; ++nt) bias[nt] = bo[n0 + nt * 16 + c];

    const f32x4 fzero = {0.f, 0.f, 0.f, 0.f};
    f32x4 acc[4][4];
    #pragma unroll
    for (int mi = 0; mi < 4; ++mi)
        #pragma unroll
        for (int nt = 0; nt < 4; ++nt) acc[mi][nt] = fzero;

    s16x8 aA[4], bA[4], aB[4], bB[4];
    auto LOADT = [&](s16x8 (&a)[4], s16x8 (&bw)[4], int kt) {
        int kb = kt * 32;
        #pragma unroll
        for (int mi = 0; mi < 4; ++mi)
            a[mi] = *(const s16x8*)(A + (size_t)(r0 + mi * 16 + c) * EMB + kb + g * 8);
        #pragma unroll
        for (int nt = 0; nt < 4; ++nt)
            bw[nt] = *(const s16x8*)(Wb + (size_t)(n0 + nt * 16 + c) * EMB + kb + g * 8);
    };
    auto MM = [&](s16x8 (&a)[4], s16x8 (&bw)[4]) {
        #pragma unroll
        for (int mi = 0; mi < 4; ++mi)
            #pragma unroll
            for (int nt = 0; nt < 4; ++nt)
                acc[mi][nt] = MFMA16(a[mi], bw[nt], acc[mi][nt]);
    };

    LOADT(aA, bA, 0);
    for (int kt = 0; kt < EMB / 32; kt += 2) {
        LOADT(aB, bB, kt + 1);
        MM(aA, bA);
        if (kt + 2 < EMB / 32) LOADT(aA, bA, kt + 2);
        MM(aB, bB);
    }

    #pragma unroll
    for (int mi = 0; mi < 4; ++mi)
        #pragma unroll
        for (int j = 0; j < 4; ++j) {
            int row = r0 + mi * 16 + g * 4 + j;
            #pragma unroll
            for (int nt = 0; nt < 4; ++nt)
                out[(size_t)row * EMB + n0 + nt * 16 + c] = acc[mi][nt][j] + bias[nt];
        }
}

extern "C" void kernel_launch(void* const* d_in, const int* in_sizes, int n_in,
                              void* d_out, int out_size, void* d_ws, size_t ws_size,
                              hipStream_t stream) {
    (void)in_sizes; (void)n_in; (void)out_size; (void)ws_size;
    const float* values  = (const float*)d_in[0];
    const float* keys    = (const float*)d_in[1];
    const float* queries = (const float*)d_in[2];
    const int*   mask    = (const int*)d_in[3];
    const float* Wv = (const float*)d_in[4];
    const float* Wk = (const float*)d_in[5];
    const float* Wq = (const float*)d_in[6];
    const float* Wo = (const float*)d_in[7];
    const float* bo = (const float*)d_in[8];
    float* out = (float*)d_out;

    // ws: Qp, Kp, Vt, Oa (16 MiB each), Wb (2 MiB), Mp (2 MiB), W3 (3x8 KiB)
    unsigned short* Qp = (unsigned short*)d_ws;
    unsigned short* Kp = Qp + (size_t)8 * 1024 * 1024;
    unsigned short* Vt = Kp + (size_t)8 * 1024 * 1024;
    unsigned short* Oa = Vt + (size_t)8 * 1024 * 1024;
    unsigned short* Wb = Oa + (size_t)8 * 1024 * 1024;
    unsigned long long* Mp = (unsigned long long*)(Wb + (size_t)1024 * 1024);
    unsigned short* Wq3 = (unsigned short*)(Mp + (size_t)262144);
    unsigned short* Wk3 = Wq3 + 4096;
    unsigned short* Wv3 = Wk3 + 4096;

    const float QSCALE = 0.045084220027780106f;   // log2(e) / sqrt(1024)

    cvt_wo<<<1024, 256, 0, stream>>>(Wo, Wb);
    cvt_wo<<<4, 256, 0, stream>>>(Wq, Wq3);
    cvt_wo<<<4, 256, 0, stream>>>(Wk, Wk3);
    cvt_wo<<<4, 256, 0, stream>>>(Wv, Wv3);
    packmask<<<4096, 256, 0, stream>>>(mask, Mp);
    projqk<<<2048, 256, 0, stream>>>(queries, Wq3, Qp, QSCALE);
    projqk<<<2048, 256, 0, stream>>>(keys,    Wk3, Kp, 1.0f);
    projv<<<dim3(32, 64), 256, 0, stream>>>(values, Wv3, Vt);
    attn<<<dim3(32, 64), 256, 0, stream>>>(Qp, Kp, Vt, Mp, Oa);
    outproj<<<dim3(32, 16), 256, 0, stream>>>(Oa, Wb, bo, out);
}

// Round 8
// 423.727 us; speedup vs baseline: 2.0737x; 1.8389x over previous
//
#include <hip/hip_runtime.h>
#include <hip/hip_bf16.h>

#define S_LEN 2048
#define NHEAD 16
#define DHEAD 64
#define EMB   1024
#define NB    4
#define KBLK  64
#define NT    (S_LEN / KBLK)   // 32

typedef short s16x8 __attribute__((ext_vector_type(8)));
typedef float f32x4 __attribute__((ext_vector_type(4)));

#define MFMA16(a, b, c) __builtin_amdgcn_mfma_f32_16x16x32_bf16(a, b, c, 0, 0, 0)

#if __has_builtin(__builtin_amdgcn_exp2f)
#define EXP2(x) __builtin_amdgcn_exp2f(x)
#else
#define EXP2(x) exp2f(x)
#endif

__device__ inline unsigned short f2bf(float f) {
    return __builtin_bit_cast(unsigned short, __float2bfloat16(f));
}

__device__ inline s16x8 cvt8(const float* __restrict__ p) {
    const f32x4* q = (const f32x4*)p;
    f32x4 a = q[0], b = q[1];
    s16x8 r;
    r[0] = (short)f2bf(a[0]); r[1] = (short)f2bf(a[1]);
    r[2] = (short)f2bf(a[2]); r[3] = (short)f2bf(a[3]);
    r[4] = (short)f2bf(b[0]); r[5] = (short)f2bf(b[1]);
    r[6] = (short)f2bf(b[2]); r[7] = (short)f2bf(b[3]);
    return r;
}

// K0: f32 -> bf16 copy, 4 elems/thread
__global__ __launch_bounds__(256) void cvt_wo(const float* __restrict__ Wo,
                                              unsigned short* __restrict__ Wb) {
    int i = (blockIdx.x * 256 + threadIdx.x) * 4;
    f32x4 v = *(const f32x4*)(Wo + i);
    unsigned long long pk = (unsigned long long)f2bf(v[0])
                          | ((unsigned long long)f2bf(v[1]) << 16)
                          | ((unsigned long long)f2bf(v[2]) << 32)
                          | ((unsigned long long)f2bf(v[3]) << 48);
    *(unsigned long long*)(Wb + i) = pk;
}

// K1: pack mask int32 -> bit mask
__global__ __launch_bounds__(256) void packmask(const int* __restrict__ mask,
                                                unsigned long long* __restrict__ Mp) {
    int wid0 = (blockIdx.x * 4 + ((int)threadIdx.x >> 6)) * 16;
    int lane = threadIdx.x & 63;
    #pragma unroll 8
    for (int i = 0; i < 16; ++i) {
        size_t w = (size_t)wid0 + i;
        int m = mask[w * 64 + lane];
        unsigned long long bal = __ballot(m != 0);
        if (lane == 0) Mp[w] = bal;
    }
}

// K2: Q/K projection (W pre-converted bf16)
__global__ __launch_bounds__(256) void projqk(const float* __restrict__ x,
                                              const unsigned short* __restrict__ W3,
                                              unsigned short* __restrict__ out,
                                              float scale) {
    int wave = threadIdx.x >> 6, lane = threadIdx.x & 63;
    int g = lane >> 4, c = lane & 15;
    int m0 = (blockIdx.x * 4 + wave) * 16;

    s16x8 a0 = cvt8(x + (size_t)(m0 + c) * 64 + g * 8);
    s16x8 a1 = cvt8(x + (size_t)(m0 + c) * 64 + 32 + g * 8);

    const f32x4 fzero = {0.f, 0.f, 0.f, 0.f};
    f32x4 acc[4];
    #pragma unroll
    for (int nt = 0; nt < 4; ++nt) {
        s16x8 b0 = *(const s16x8*)(W3 + (size_t)(nt * 16 + c) * 64 + g * 8);
        s16x8 b1 = *(const s16x8*)(W3 + (size_t)(nt * 16 + c) * 64 + 32 + g * 8);
        f32x4 z = fzero;
        z = MFMA16(a0, b0, z);
        z = MFMA16(a1, b1, z);
        acc[nt] = z;
    }
    #pragma unroll
    for (int j = 0; j < 4; ++j) {
        int m = m0 + g * 4 + j;
        int h = m & 15, s = (m >> 4) & (S_LEN - 1), b = m >> 15;
        #pragma unroll
        for (int nt = 0; nt < 4; ++nt) {
            int col = nt * 16 + c;
            out[((size_t)((b * NHEAD + h) * S_LEN + s)) * DHEAD + col] = f2bf(acc[nt][j] * scale);
        }
    }
}

// K3: V projection, written transposed: Vt[((b*H+h)*64+e)*S + s]
__global__ __launch_bounds__(256) void projv(const float* __restrict__ x,
                                             const unsigned short* __restrict__ W3,
                                             unsigned short* __restrict__ Vt) {
    int wave = threadIdx.x >> 6, lane = threadIdx.x & 63;
    int g = lane >> 4, c = lane & 15;
    int s0 = blockIdx.x * 64;
    int bh = blockIdx.y, b = bh >> 4, h = bh & 15;
    int m0 = wave * 16;

    s16x8 a0 = *(const s16x8*)(W3 + (size_t)(m0 + c) * 64 + g * 8);
    s16x8 a1 = *(const s16x8*)(W3 + (size_t)(m0 + c) * 64 + 32 + g * 8);

    const f32x4 fzero = {0.f, 0.f, 0.f, 0.f};
    f32x4 acc[4];
    #pragma unroll
    for (int nt = 0; nt < 4; ++nt) {
        int s = s0 + nt * 16 + c;
        const float* xr = x + ((size_t)(b * S_LEN + s) * NHEAD + h) * DHEAD;
        s16x8 b0 = cvt8(xr + g * 8);
        s16x8 b1 = cvt8(xr + 32 + g * 8);
        f32x4 z = fzero;
        z = MFMA16(a0, b0, z);
        z = MFMA16(a1, b1, z);
        acc[nt] = z;
    }
    #pragma unroll
    for (int j = 0; j < 4; ++j) {
        int e = m0 + g * 4 + j;
        unsigned short* Vr = Vt + ((size_t)(bh * DHEAD) + e) * S_LEN;
        #pragma unroll
        for (int nt = 0; nt < 4; ++nt) {
            Vr[s0 + nt * 16 + c] = f2bf(acc[nt][j]);
        }
    }
}

// K4: flash attention. 1024 flat blocks, XCD-grouped: all 16 q-blocks of a head
// run on one XCD (K/V 512KB stays L2-resident). Q-tile 128/block, 32 rows/wave.
// K/V staged once per block into LDS in FRAGMENT ORDER [subtile][lane][16B]
// (pre-permuted so ds_read_b128 is the native linear pattern - no conflicts,
// rule #21 both-sides handled at the write address). 2-barrier double buffer,
// global->reg issue before compute, reg->LDS after barrier (T14 split).
__global__ __launch_bounds__(256, 3) void attn(const unsigned short* __restrict__ Qp,
                                               const unsigned short* __restrict__ Kp,
                                               const unsigned short* __restrict__ Vt,
                                               const unsigned long long* __restrict__ Mp,
                                               unsigned short* __restrict__ Oa) {
    __shared__ unsigned short Kl[2][8][64][8];   // 16 KiB: [buf][nt*2+khalf][g*16+c][8]
    __shared__ unsigned short Vl[2][8][64][8];   // 16 KiB
    __shared__ unsigned short Pl[4][2][16 * 72]; // 18 KiB: per wave, per mi

    int tid = threadIdx.x;
    int wave = tid >> 6, lane = tid & 63, g = lane >> 4, c = lane & 15;
    int bid = blockIdx.x;
    int xcd = bid & 7, idx = bid >> 3;           // bijective: 1024 % 8 == 0
    int bh = xcd * 8 + (idx >> 4);               // 8 heads per XCD, consecutive blocks same head
    int qblk = idx & 15;
    int b = bh >> 4, h = bh & 15;
    int q0 = qblk * 128 + wave * 32;

    const unsigned short* Qb = Qp + (size_t)bh * S_LEN * DHEAD;
    const unsigned short* Kb = Kp + (size_t)bh * S_LEN * DHEAD;
    const unsigned short* Vb = Vt + (size_t)bh * DHEAD * S_LEN;
    const unsigned long long* mb = Mp + (size_t)b * S_LEN * NT;

    s16x8 aq[2][2];
    #pragma unroll
    for (int mi = 0; mi < 2; ++mi) {
        aq[mi][0] = *(const s16x8*)(Qb + (size_t)(q0 + mi * 16 + c) * 64 + g * 8);
        aq[mi][1] = *(const s16x8*)(Qb + (size_t)(q0 + mi * 16 + c) * 64 + 32 + g * 8);
    }

    // staging: thread t owns K chunks {2t, 2t+1} and V chunks {2t, 2t+1}
    // chunk cid: row r = cid>>3 (kpos for K, d for V), 16B col-chunk ch = cid&7
    int cid = tid * 2;
    int kr = cid >> 3, kch = cid & 7;
    const unsigned short* Ksrc = Kb + (size_t)kr * 64 + kch * 8;
    const unsigned short* Vsrc = Vb + (size_t)kr * S_LEN + kch * 8;
    unsigned short* Kd0 = &Kl[0][(kr >> 4) * 2 + (kch >> 2)][(kch & 3) * 16 + (kr & 15)][0];
    unsigned short* Kd1 = &Kl[0][(kr >> 4) * 2 + ((kch + 1) >> 2)][((kch + 1) & 3) * 16 + (kr & 15)][0];
    unsigned short* Vd0 = &Vl[0][(kr >> 4) * 2 + (kch >> 2)][(kch & 3) * 16 + (kr & 15)][0];
    unsigned short* Vd1 = &Vl[0][(kr >> 4) * 2 + ((kch + 1) >> 2)][((kch + 1) & 3) * 16 + (kr & 15)][0];

    const f32x4 fzero = {0.f, 0.f, 0.f, 0.f};
    f32x4 acc[2][4], accl[2];
    #pragma unroll
    for (int mi = 0; mi < 2; ++mi) {
        accl[mi] = fzero;
        #pragma unroll
        for (int nt = 0; nt < 4; ++nt) acc[mi][nt] = fzero;
    }
    s16x8 ones;
    #pragma unroll
    for (int i = 0; i < 8; ++i) ones[i] = (short)0x3F80;   // bf16 1.0

    s16x8 gk0, gk1, gv0, gv1;
    auto LOADR = [&](int kt) {
        size_t k0 = (size_t)kt * KBLK;
        gk0 = *(const s16x8*)(Ksrc + k0 * 64);
        gk1 = *(const s16x8*)(Ksrc + k0 * 64 + 8);
        gv0 = *(const s16x8*)(Vsrc + k0);
        gv1 = *(const s16x8*)(Vsrc + k0 + 8);
    };
    auto STAGEW = [&](int bufv) {
        int off = bufv * 4096;   // shorts per buffer: 8*64*8
        *(s16x8*)(Kd0 + off) = gk0;
        *(s16x8*)(Kd1 + off) = gk1;
        *(s16x8*)(Vd0 + off) = gv0;
        *(s16x8*)(Vd1 + off) = gv1;
    };

    auto COMPUTE = [&](int bufv, int kt) {
        unsigned long long mw[2][4];
        #pragma unroll
        for (int mi = 0; mi < 2; ++mi)
            #pragma unroll
            for (int j = 0; j < 4; ++j)
                mw[mi][j] = mb[(size_t)(q0 + mi * 16 + g * 4 + j) * NT + kt];

        f32x4 sc[2][4];
        #pragma unroll
        for (int nt = 0; nt < 4; ++nt) {
            s16x8 kf0 = *(const s16x8*)&Kl[bufv][nt * 2][lane][0];
            s16x8 kf1 = *(const s16x8*)&Kl[bufv][nt * 2 + 1][lane][0];
            #pragma unroll
            for (int mi = 0; mi < 2; ++mi) {
                f32x4 z = MFMA16(aq[mi][0], kf0, fzero);
                sc[mi][nt] = MFMA16(aq[mi][1], kf1, z);
            }
        }
        #pragma unroll
        for (int mi = 0; mi < 2; ++mi) {
            unsigned short* Pw = &Pl[wave][mi][0];
            #pragma unroll
            for (int j = 0; j < 4; ++j) {
                unsigned wlo = (unsigned)mw[mi][j];
                unsigned whi = (unsigned)(mw[mi][j] >> 32);
                int r = g * 4 + j;
                #pragma unroll
                for (int nt = 0; nt < 4; ++nt) {
                    float e = EXP2(sc[mi][nt][j]);
                    unsigned part = (nt < 2) ? wlo : whi;
                    float p = e * (float)((part >> ((nt & 1) * 16 + c)) & 1u);
                    Pw[r * 72 + nt * 16 + c] = f2bf(p);
                }
            }
        }
        s16x8 ap[2][2];
        #pragma unroll
        for (int mi = 0; mi < 2; ++mi) {
            const unsigned short* Pw = &Pl[wave][mi][0];
            ap[mi][0] = *(const s16x8*)(Pw + c * 72 + g * 8);
            ap[mi][1] = *(const s16x8*)(Pw + c * 72 + 32 + g * 8);
            accl[mi] = MFMA16(ap[mi][0], ones, accl[mi]);
            accl[mi] = MFMA16(ap[mi][1], ones, accl[mi]);
        }
        #pragma unroll
        for (int nt = 0; nt < 4; ++nt) {
            s16x8 vf0 = *(const s16x8*)&Vl[bufv][nt * 2][lane][0];
            s16x8 vf1 = *(const s16x8*)&Vl[bufv][nt * 2 + 1][lane][0];
            #pragma unroll
            for (int mi = 0; mi < 2; ++mi) {
                acc[mi][nt] = MFMA16(ap[mi][0], vf0, acc[mi][nt]);
                acc[mi][nt] = MFMA16(ap[mi][1], vf1, acc[mi][nt]);
            }
        }
    };

    LOADR(0);
    STAGEW(0);
    __syncthreads();
    for (int kt = 0; kt < NT; ++kt) {
        int cur = kt & 1;
        if (kt + 1 < NT) LOADR(kt + 1);      // HBM/L2 latency hides under compute
        COMPUTE(cur, kt);
        __syncthreads();                     // all waves done reading buf[cur]
        if (kt + 1 < NT) {
            STAGEW(cur ^ 1);
            __syncthreads();                 // next tile visible
        }
    }

    #pragma unroll
    for (int mi = 0; mi < 2; ++mi)
        #pragma unroll
        for (int j = 0; j < 4; ++j) {
            int q = q0 + mi * 16 + g * 4 + j;
            float inv = 1.f / accl[mi][j];
            #pragma unroll
            for (int nt = 0; nt < 4; ++nt)
                Oa[((size_t)(b * S_LEN + q)) * EMB + h * DHEAD + nt * 16 + c] = f2bf(acc[mi][nt][j] * inv);
        }
}

// K5: out = Oa(8192x1024,bf16) @ Wo^T + bo. Flat 512 grid, XCD-grouped by row-panel.
__global__ __launch_bounds__(256, 2) void outproj(const unsigned short* __restrict__ A,
                                                  const unsigned short* __restrict__ Wb,
                                                  const float* __restrict__ bo,
                                                  float* __restrict__ out) {
    int wave = threadIdx.x >> 6, lane = threadIdx.x & 63;
    int g = lane >> 4, c = lane & 15;
    int bid = blockIdx.x;
    int xcd = bid & 7, idx = bid >> 3;           // 512 % 8 == 0, bijective
    int bx = xcd * 4 + (idx >> 4);               // 32 row-tiles, 4 per XCD
    int by = idx & 15;                            // 16 col-tiles
    int r0 = bx * 256 + wave * 64;
    int n0 = by * 64;

    float bias[4];
    #pragma unroll
    for (int nt = 0; nt < 4; ++nt) bias[nt] = bo[n0 + nt * 16 + c];

    const f32x4 fzero = {0.f, 0.f, 0.f, 0.f};
    f32x4 acc[4][4];
    #pragma unroll
    for (int mi = 0; mi < 4; ++mi)
        #pragma unroll
        for (int nt = 0; nt < 4; ++nt) acc[mi][nt] = fzero;

    s16x8 aA[4], bA[4], aB[4], bB[4];
    auto LOADT = [&](s16x8 (&a)[4], s16x8 (&bw)[4], int kt) {
        int kb = kt * 32;
        #pragma unroll
        for (int mi = 0; mi < 4; ++mi)
            a[mi] = *(const s16x8*)(A + (size_t)(r0 + mi * 16 + c) * EMB + kb + g * 8);
        #pragma unroll
        for (int nt = 0; nt < 4; ++nt)
            bw[nt] = *(const s16x8*)(Wb + (size_t)(n0 + nt * 16 + c) * EMB + kb + g * 8);
    };
    auto MM = [&](s16x8 (&a)[4], s16x8 (&bw)[4]) {
        #pragma unroll
        for (int mi = 0; mi < 4; ++mi)
            #pragma unroll
            for (int nt = 0; nt < 4; ++nt)
                acc[mi][nt] = MFMA16(a[mi], bw[nt], acc[mi][nt]);
    };

    LOADT(aA, bA, 0);
    for (int kt = 0; kt < EMB / 32; kt += 2) {
        LOADT(aB, bB, kt + 1);
        MM(aA, bA);
        if (kt + 2 < EMB / 32) LOADT(aA, bA, kt + 2);
        MM(aB, bB);
    }

    #pragma unroll
    for (int mi = 0; mi < 4; ++mi)
        #pragma unroll
        for (int j = 0; j < 4; ++j) {
            int row = r0 + mi * 16 + g * 4 + j;
            #pragma unroll
            for (int nt = 0; nt < 4; ++nt)
                out[(size_t)row * EMB + n0 + nt * 16 + c] = acc[mi][nt][j] + bias[nt];
        }
}

extern "C" void kernel_launch(void* const* d_in, const int* in_sizes, int n_in,
                              void* d_out, int out_size, void* d_ws, size_t ws_size,
                              hipStream_t stream) {
    (void)in_sizes; (void)n_in; (void)out_size; (void)ws_size;
    const float* values  = (const float*)d_in[0];
    const float* keys    = (const float*)d_in[1];
    const float* queries = (const float*)d_in[2];
    const int*   mask    = (const int*)d_in[3];
    const float* Wv = (const float*)d_in[4];
    const float* Wk = (const float*)d_in[5];
    const float* Wq = (const float*)d_in[6];
    const float* Wo = (const float*)d_in[7];
    const float* bo = (const float*)d_in[8];
    float* out = (float*)d_out;

    unsigned short* Qp = (unsigned short*)d_ws;
    unsigned short* Kp = Qp + (size_t)8 * 1024 * 1024;
    unsigned short* Vt = Kp + (size_t)8 * 1024 * 1024;
    unsigned short* Oa = Vt + (size_t)8 * 1024 * 1024;
    unsigned short* Wb = Oa + (size_t)8 * 1024 * 1024;
    unsigned long long* Mp = (unsigned long long*)(Wb + (size_t)1024 * 1024);
    unsigned short* Wq3 = (unsigned short*)(Mp + (size_t)262144);
    unsigned short* Wk3 = Wq3 + 4096;
    unsigned short* Wv3 = Wk3 + 4096;

    const float QSCALE = 0.045084220027780106f;   // log2(e) / sqrt(1024)

    cvt_wo<<<1024, 256, 0, stream>>>(Wo, Wb);
    cvt_wo<<<4, 256, 0, stream>>>(Wq, Wq3);
    cvt_wo<<<4, 256, 0, stream>>>(Wk, Wk3);
    cvt_wo<<<4, 256, 0, stream>>>(Wv, Wv3);
    packmask<<<4096, 256, 0, stream>>>(mask, Mp);
    projqk<<<2048, 256, 0, stream>>>(queries, Wq3, Qp, QSCALE);
    projqk<<<2048, 256, 0, stream>>>(keys,    Wk3, Kp, 1.0f);
    projv<<<dim3(32, 64), 256, 0, stream>>>(values, Wv3, Vt);
    attn<<<1024, 256, 0, stream>>>(Qp, Kp, Vt, Mp, Oa);
    outproj<<<512, 256, 0, stream>>>(Oa, Wb, bo, out);
}